// Round 5
// baseline (3410.706 us; speedup 1.0000x reference)
//
#include <hip/hip_runtime.h>

// CompetitiveLayer: K = param^2 (4096x4096 f32), 21 iterations of
//   AF = AT/(1+K@BF); BF = BT/(1+AF@K); then C = K * AF[:,None] * BF[None,:].
//
// R2-R4 post-mortem: per-lane K-in-VGPR designs all spilled (allocator caps
// at its occupancy heuristic; VGPR_Count 168/120 < array size) -> latency-
// bound scratch re-reads, 1.6-2.6 ms.
//
// R5 design: block b owns ROWS [16b,16b+16) of K, stored in LDS as f16
// (padded stride). Row matvec (AF) is block-local (no cross-block reduce);
// col partials AF@K are atomicAdd'ed into a global denominator -> ONE grid
// sync per iteration (21 total, was 42). K read from HBM exactly once.

constexpr int N       = 4096;
constexpr int NITER   = 21;
constexpr int NBLK    = 256;
constexpr int ROWS    = 16;
constexpr int TSTRIDE = 4104;   // f16 elements per padded LDS row (+8 pad)

typedef _Float16 half2t __attribute__((ext_vector_type(2)));

union V16 { uint4 u; half2t h[4]; _Float16 f[8]; };
union PK  { half2t h; uint u; };

__device__ __forceinline__ float ld_agent(const float* p) {
    return __hip_atomic_load(p, __ATOMIC_RELAXED, __HIP_MEMORY_SCOPE_AGENT);
}
__device__ __forceinline__ void st_agent(float* p, float v) {
    __hip_atomic_store(p, v, __ATOMIC_RELAXED, __HIP_MEMORY_SCOPE_AGENT);
}

__device__ __forceinline__ float dot2(half2t a, half2t b, float c) {
#if __has_builtin(__builtin_amdgcn_fdot2)
    return __builtin_amdgcn_fdot2(a, b, c, false);
#else
    return fmaf((float)a.x, (float)b.x, fmaf((float)a.y, (float)b.y, c));
#endif
}

__global__ void __launch_bounds__(256)
competitive_persistent(const float* __restrict__ AT, const float* __restrict__ BT,
                       const float* __restrict__ P,  float* __restrict__ C,
                       float* __restrict__ ws)
{
    // 131328 + 8192 + 64 = 139584 B <= 163840 B LDS/CU -> 1 block/CU.
    __shared__ ushort tile[ROWS * TSTRIDE];   // K rows, f16, padded stride
    __shared__ uint   bfh[N / 2];             // BF packed f16x2
    __shared__ float  afs[ROWS];              // AF slice (persists to epilogue)

    const int b  = blockIdx.x;       // 0..255
    const int t  = threadIdx.x;      // 0..255
    const int R0 = b * ROWS;

    unsigned* bar = (unsigned*)(ws + 3 * (size_t)N);   // host-zeroed

    // ---- One-time: load P rows, square, convert f16, stage into LDS ----
    {
        const float4* src = (const float4*)(P + (size_t)R0 * N);
        #pragma unroll 4
        for (int j = 0; j < 64; ++j) {
            const int idx4 = t + 256 * j;         // float4 idx in 16x4096
            float4 v = src[idx4];
            const int fi = idx4 * 4;
            const int r = fi >> 12, c = fi & 4095;
            PK p0, p1;
            p0.h = half2t{ (_Float16)(v.x * v.x), (_Float16)(v.y * v.y) };
            p1.h = half2t{ (_Float16)(v.z * v.z), (_Float16)(v.w * v.w) };
            uint2 u; u.x = p0.u; u.y = p1.u;
            *(uint2*)(tile + r * TSTRIDE + c) = u;   // 8-B aligned (c%4==0)
        }
    }

    const int chunk = t & 15;             // col-chunk id
    const int s     = t >> 4;             // 0..15
    const int c0    = chunk * 16 + s * 256;  // this thread's 16 cols
    const int rot   = (t >> 4) & 3;       // row rotation (bank spread)

    // den buffers: iter it reads buf[it%3], accumulates buf[(it+1)%3],
    // zeroes buf[(it+2)%3]. buf0 zero at entry -> BF_0 = BT (matches ref).
    #pragma unroll 1
    for (int it = 0; it < NITER; ++it) {
        const float* den = ws + (size_t)N * (it % 3);
        float*       acc = ws + (size_t)N * ((it + 1) % 3);
        float*       zb  = ws + (size_t)N * ((it + 2) % 3);

        // ---- Stage BF = BT/(1+den) as f16 into LDS (16 cols/thread) ----
        {
            float bf[16];
            #pragma unroll
            for (int m = 0; m < 16; ++m)
                bf[m] = BT[c0 + m] / (1.0f + ld_agent(den + c0 + m));
            #pragma unroll
            for (int m = 0; m < 8; ++m) {
                PK p; p.h = half2t{ (_Float16)bf[2 * m], (_Float16)bf[2 * m + 1] };
                bfh[(c0 >> 1) + m] = p.u;
            }
        }
        if (t < 16) st_agent(zb + b * 16 + t, 0.0f);
        __syncthreads();

        // ---- Row matvec: AF[row] = AT/(1 + K[row,:]@BF) ----
        {
            const int row = t >> 4;       // 16 threads per row
            const int ch  = t & 15;
            const ushort* krow = tile + row * TSTRIDE;
            float a = 0.0f;
            #pragma unroll
            for (int ss = 0; ss < 16; ++ss) {
                const int col = ss * 256 + ch * 16;
                V16 k0, k1, x0, x1;
                k0.u = *(const uint4*)(krow + col);
                k1.u = *(const uint4*)(krow + col + 8);
                x0.u = *(const uint4*)(bfh + (col >> 1));
                x1.u = *(const uint4*)(bfh + (col >> 1) + 4);
                #pragma unroll
                for (int m = 0; m < 4; ++m) a = dot2(k0.h[m], x0.h[m], a);
                #pragma unroll
                for (int m = 0; m < 4; ++m) a = dot2(k1.h[m], x1.h[m], a);
            }
            a += __shfl_xor(a, 1, 64);
            a += __shfl_xor(a, 2, 64);
            a += __shfl_xor(a, 4, 64);
            a += __shfl_xor(a, 8, 64);
            if (ch == 0) afs[row] = AT[R0 + row] / (1.0f + a);
        }
        __syncthreads();

        // ---- Col partials: acc[j] += sum_r AF[r]*K[r,j] (16 cols/thread) ----
        {
            float pacc[16];
            #pragma unroll
            for (int m = 0; m < 16; ++m) pacc[m] = 0.0f;
            #pragma unroll
            for (int rr = 0; rr < 16; ++rr) {
                const int row = (rr + rot) & 15;        // spread LDS banks
                const float a = afs[row];
                V16 k0, k1;
                k0.u = *(const uint4*)(tile + row * TSTRIDE + c0);
                k1.u = *(const uint4*)(tile + row * TSTRIDE + c0 + 8);
                #pragma unroll
                for (int m = 0; m < 8; ++m)
                    pacc[m]     = fmaf((float)k0.f[m], a, pacc[m]);
                #pragma unroll
                for (int m = 0; m < 8; ++m)
                    pacc[8 + m] = fmaf((float)k1.f[m], a, pacc[8 + m]);
            }
            #pragma unroll
            for (int m = 0; m < 16; ++m)
                atomicAdd(acc + c0 + m, pacc[m]);       // 256-way, mem-side
        }

        // ---- Grid barrier (monotonic counter) ----
        __threadfence();
        __syncthreads();
        if (t == 0) {
            __hip_atomic_fetch_add(bar, 1u, __ATOMIC_ACQ_REL,
                                   __HIP_MEMORY_SCOPE_AGENT);
            const unsigned target = (unsigned)(NBLK * (it + 1));
            while (__hip_atomic_load(bar, __ATOMIC_ACQUIRE,
                                     __HIP_MEMORY_SCOPE_AGENT) < target)
                __builtin_amdgcn_s_sleep(2);
        }
        __syncthreads();
    }

    // ---- Epilogue: C = K * AF[:,None] * BF[None,:] ----
    // den_21 landed in buf[(20+1)%3] = buf0. afs holds the final AF slice.
    {
        const float* den = ws;            // buf0
        float bf[16];
        #pragma unroll
        for (int m = 0; m < 16; ++m)
            bf[m] = BT[c0 + m] / (1.0f + ld_agent(den + c0 + m));

        #pragma unroll 2
        for (int rr = 0; rr < 16; ++rr) {
            const int row = (rr + rot) & 15;
            const float a = afs[row];
            V16 k0, k1;
            k0.u = *(const uint4*)(tile + row * TSTRIDE + c0);
            k1.u = *(const uint4*)(tile + row * TSTRIDE + c0 + 8);
            float4* dst = (float4*)(C + (size_t)(R0 + row) * N + c0);
            float4 o;
            o.x = (float)k0.f[0] * a * bf[0];  o.y = (float)k0.f[1] * a * bf[1];
            o.z = (float)k0.f[2] * a * bf[2];  o.w = (float)k0.f[3] * a * bf[3];
            dst[0] = o;
            o.x = (float)k0.f[4] * a * bf[4];  o.y = (float)k0.f[5] * a * bf[5];
            o.z = (float)k0.f[6] * a * bf[6];  o.w = (float)k0.f[7] * a * bf[7];
            dst[1] = o;
            o.x = (float)k1.f[0] * a * bf[8];  o.y = (float)k1.f[1] * a * bf[9];
            o.z = (float)k1.f[2] * a * bf[10]; o.w = (float)k1.f[3] * a * bf[11];
            dst[2] = o;
            o.x = (float)k1.f[4] * a * bf[12]; o.y = (float)k1.f[5] * a * bf[13];
            o.z = (float)k1.f[6] * a * bf[14]; o.w = (float)k1.f[7] * a * bf[15];
            dst[3] = o;
        }
    }
}

extern "C" void kernel_launch(void* const* d_in, const int* in_sizes, int n_in,
                              void* d_out, int out_size, void* d_ws, size_t ws_size,
                              hipStream_t stream) {
    const float* AT = (const float*)d_in[0];
    const float* BT = (const float*)d_in[1];
    const float* P  = (const float*)d_in[2];
    float*       C  = (float*)d_out;
    float*       ws = (float*)d_ws;

    // Zero the 3 rotating denominator buffers + barrier counter.
    hipMemsetAsync(d_ws, 0, (3 * (size_t)N + 16) * sizeof(float), stream);

    competitive_persistent<<<dim3(NBLK), dim3(256), 0, stream>>>(AT, BT, P, C, ws);
}

// Round 6
// 3244.389 us; speedup vs baseline: 1.0513x; 1.0513x over previous
//
#include <hip/hip_runtime.h>

// CompetitiveLayer: K = param^2 (4096x4096 f32), 21 iterations of
//   AF = AT/(1+K@BF); BF = BT/(1+AF@K); then C = K * AF[:,None] * BF[None,:].
//
// R5 post-mortem: K-rows-in-LDS(f16) structure is correct (absmax 7.6e-6)
// but 1M scattered 4-B device-scope atomicAdds + 1M scattered agent loads
// per iteration at only 4 waves/CU -> latency-bound, 158 us/iter,
// WRITE_SIZE 754 MB (32-B RMW granules). 3.4 ms.
//
// R6: (1) atomics -> two-phase allreduce: blocks STORE coalesced f32
// partials P[b][0..4095] (full-line, 4 MB/iter), barrier, block b reduces
// cols [16b,16b+16) and writes den chunk, barrier. (2) 1024 threads/block
// (16 waves/CU) for 4x latency hiding. (3) 8-way split barrier counters.

constexpr int N     = 4096;
constexpr int NITER = 21;
constexpr int NBLK  = 256;
constexpr int ROWS  = 16;
constexpr int TST   = 4104;     // padded f16 row stride in LDS

typedef _Float16 half2t __attribute__((ext_vector_type(2)));
union V16 { uint4 u; half2t h[4]; };

__device__ __forceinline__ float ld_agent(const float* p) {
    return __hip_atomic_load(p, __ATOMIC_RELAXED, __HIP_MEMORY_SCOPE_AGENT);
}
__device__ __forceinline__ void st_agent(float* p, float v) {
    __hip_atomic_store(p, v, __ATOMIC_RELAXED, __HIP_MEMORY_SCOPE_AGENT);
}

__device__ __forceinline__ float dot2(half2t a, half2t b, float c) {
#if __has_builtin(__builtin_amdgcn_fdot2)
    return __builtin_amdgcn_fdot2(a, b, c, false);
#else
    return fmaf((float)a.x, (float)b.x, fmaf((float)a.y, (float)b.y, c));
#endif
}

// Monotonic grid barrier, 8 split counters (64-B spaced). 256 blocks -> 32
// adds per counter; target = 32*bs. No reset; host zeroes before launch.
__device__ __forceinline__ void gridbar(unsigned* cnt, unsigned bs, int t) {
    __threadfence();              // release prior agent-scope stores
    __syncthreads();
    if (t == 0)
        __hip_atomic_fetch_add(cnt + ((blockIdx.x & 7) << 4), 1u,
                               __ATOMIC_ACQ_REL, __HIP_MEMORY_SCOPE_AGENT);
    if (t < 8) {
        const unsigned target = 32u * bs;
        while (__hip_atomic_load(cnt + (t << 4), __ATOMIC_ACQUIRE,
                                 __HIP_MEMORY_SCOPE_AGENT) < target)
            __builtin_amdgcn_s_sleep(2);
    }
    __syncthreads();
}

__global__ void __launch_bounds__(1024)
competitive_persistent(const float* __restrict__ AT, const float* __restrict__ BT,
                       const float* __restrict__ Pg, float* __restrict__ C,
                       float* __restrict__ ws)
{
    // LDS: 131328 + 8192 + 16384 + 64 = 155968 B <= 163840 -> 1 block/CU.
    __shared__ _Float16 tile[ROWS * TST];   // K rows, f16
    __shared__ _Float16 bfh[N];             // BF, f16
    __shared__ float    redf[N];            // phaseB reduce / epilogue BF
    __shared__ float    afs[ROWS];          // AF slice (persists)

    const int b  = blockIdx.x;              // 0..255
    const int t  = threadIdx.x;             // 0..1023
    const int R0 = b * ROWS;

    float*    den = ws;                                  // 4096 f32 (zeroed)
    unsigned* cnt = (unsigned*)(ws + N);                 // 128 u32 (zeroed)
    float*    Pp  = ws + 2 * (size_t)N;                  // 256 x 4096 f32

    // ---- One-time: load P rows, square, convert f16 into LDS ----
    {
        const float4* src = (const float4*)(Pg + (size_t)R0 * N);
        #pragma unroll
        for (int j = 0; j < 16; ++j) {
            const int idx4 = t + 1024 * j;
            float4 v = src[idx4];
            const int fi = idx4 * 4;
            const int r = fi >> 12, c = fi & 4095;
            half2t h0 = { (_Float16)(v.x * v.x), (_Float16)(v.y * v.y) };
            half2t h1 = { (_Float16)(v.z * v.z), (_Float16)(v.w * v.w) };
            *(half2t*)(tile + r * TST + c)     = h0;
            *(half2t*)(tile + r * TST + c + 2) = h1;
        }
    }

    #pragma unroll 1
    for (int it = 0; it < NITER; ++it) {
        // ---- Stage BF = BT/(1+den) as f16 (cols t+1024m: coalesced) ----
        #pragma unroll
        for (int m = 0; m < 4; ++m) {
            const int c = t + 1024 * m;
            const float bf = BT[c] / (1.0f + ld_agent(den + c));
            bfh[c] = (_Float16)bf;
        }
        __syncthreads();

        // ---- Row matvec: one wave per row, 64 lanes x 64 cols ----
        {
            const int row = t >> 6, l = t & 63;
            const _Float16* krow = tile + row * TST;
            float a = 0.0f;
            #pragma unroll
            for (int w = 0; w < 8; ++w) {
                const int col = (w * 64 + l) * 8;
                V16 kv, xv;
                kv.u = *(const uint4*)(krow + col);
                xv.u = *(const uint4*)(bfh + col);
                #pragma unroll
                for (int mm = 0; mm < 4; ++mm) a = dot2(kv.h[mm], xv.h[mm], a);
            }
            #pragma unroll
            for (int off = 1; off < 64; off <<= 1)
                a += __shfl_xor(a, off, 64);
            if (l == 0) afs[row] = AT[R0 + row] / (1.0f + a);
        }
        __syncthreads();

        // ---- Col partials: 4 cols/thread (t+1024m), coalesced stores ----
        {
            float pa[4] = {0.f, 0.f, 0.f, 0.f};
            #pragma unroll
            for (int r = 0; r < 16; ++r) {
                const float a = afs[r];
                const _Float16* krow = tile + r * TST;
                #pragma unroll
                for (int m = 0; m < 4; ++m)
                    pa[m] = fmaf((float)krow[t + 1024 * m], a, pa[m]);
            }
            float* myP = Pp + (size_t)b * N;
            #pragma unroll
            for (int m = 0; m < 4; ++m)
                st_agent(myP + t + 1024 * m, pa[m]);
        }

        gridbar(cnt, 2 * it + 1, t);

        // ---- Reduce cols [16b,16b+16) over 256 partial rows ----
        {
            const int r = t & 255, grp = t >> 8;        // 4 cols per thread
            const float* prow = Pp + (size_t)r * N + 16 * b + grp * 4;
            #pragma unroll
            for (int j = 0; j < 4; ++j)
                redf[(grp * 4 + j) * 256 + r] = ld_agent(prow + j);
            __syncthreads();
            const int cp = t >> 6, l = t & 63;          // wave cp, col cp
            float s = redf[cp * 256 + l]       + redf[cp * 256 + 64 + l]
                    + redf[cp * 256 + 128 + l] + redf[cp * 256 + 192 + l];
            #pragma unroll
            for (int off = 1; off < 64; off <<= 1)
                s += __shfl_xor(s, off, 64);
            if (l == 0) st_agent(den + 16 * b + cp, s);
        }

        gridbar(cnt, 2 * it + 2, t);
    }

    // ---- Epilogue: C = K * AF[:,None] * BF[None,:] ----
    #pragma unroll
    for (int m = 0; m < 4; ++m) {
        const int c = t + 1024 * m;
        redf[c] = BT[c] / (1.0f + ld_agent(den + c));    // final BF, f32
    }
    __syncthreads();
    {
        const int row = t >> 6, l = t & 63;
        const float a = afs[row];
        const _Float16* krow = tile + row * TST;
        float* crow = C + (size_t)(R0 + row) * N;
        #pragma unroll
        for (int w = 0; w < 16; ++w) {
            const int col = w * 256 + l * 4;
            V16 kv;
            kv.u.x = ((const uint*)(krow + col))[0];
            kv.u.y = ((const uint*)(krow + col))[1];
            const float4 bf4 = *(const float4*)(redf + col);
            float4 o;
            o.x = (float)kv.h[0].x * a * bf4.x;
            o.y = (float)kv.h[0].y * a * bf4.y;
            o.z = (float)kv.h[1].x * a * bf4.z;
            o.w = (float)kv.h[1].y * a * bf4.w;
            *(float4*)(crow + col) = o;
        }
    }
}

extern "C" void kernel_launch(void* const* d_in, const int* in_sizes, int n_in,
                              void* d_out, int out_size, void* d_ws, size_t ws_size,
                              hipStream_t stream) {
    const float* AT = (const float*)d_in[0];
    const float* BT = (const float*)d_in[1];
    const float* P  = (const float*)d_in[2];
    float*       C  = (float*)d_out;
    float*       ws = (float*)d_ws;

    // Zero den (16 KB) + barrier counters (512 B). Partial buffer needs no init.
    hipMemsetAsync(d_ws, 0, 2 * (size_t)N * sizeof(float), stream);

    competitive_persistent<<<dim3(NBLK), dim3(1024), 0, stream>>>(AT, BT, P, C, ws);
}